// Round 4
// baseline (152.361 us; speedup 1.0000x reference)
//
#include <hip/hip_runtime.h>
#include <hip/hip_cooperative_groups.h>
#include <math.h>

namespace cg = cooperative_groups;

#define BB 4
#define NN 4096
#define KK 64
#define TPB 256
#define GRID 256          // 1 block per CU, all co-resident
#define BPB 64            // repulsion blocks per batch (GRID/BB)
#define JT 32             // repulsion j-tile

__global__ __launch_bounds__(TPB) void kAll(
    const float* __restrict__ beta, const float* __restrict__ embed,
    const int* __restrict__ sid_g, const int* __restrict__ cp_g,
    float* __restrict__ cpemb, float* __restrict__ cpsq,
    float* __restrict__ gbase, float* __restrict__ gpos,
    float* __restrict__ grep, int* __restrict__ gcpn,
    float* __restrict__ out)
{
    cg::grid_group grid = cg::this_grid();
    const int blk  = blockIdx.x;
    const int t    = threadIdx.x;
    const int lane = t & 63;
    const int wid  = t >> 6;

    __shared__ int   s_first[KK];
    __shared__ int   s_counts[KK];
    __shared__ float s_seg[KK];
    __shared__ float s_fe[KK][8];
    __shared__ float s_red[3][4];
    __shared__ int   s_cpn;
    __shared__ float s_je[JT * 8];
    __shared__ float s_jq[JT];
    __shared__ float s_r[4];

    // ================= phase 1: per-batch stats (blocks 0..3) ================
    if (blk < BB) {
        const int b = blk;
        if (t < KK) { s_first[t] = NN; s_counts[t] = 0; s_seg[t] = 0.f; }
        if (t == 0) s_cpn = 0;
        __syncthreads();

        const int4*   sid4p = (const int4*)(sid_g + (size_t)b * NN);
        const int4*   cp4p  = (const int4*)(cp_g + (size_t)b * NN);
        const float4* b4p   = (const float4*)(beta + (size_t)b * NN);
        const float*  emb_b = embed + (size_t)b * NN * 8;

        int4 sids[4];
        int  slots[16];
        float a1 = 0.f, a2 = 0.f;   // sum sp(-b) over y=1, sum sp(b) over y=0
        int posl = 0;

        #pragma unroll
        for (int k = 0; k < 4; ++k) {
            int idx4 = k * TPB + t;          // 4-elem group index (coalesced)
            int4 s4 = sid4p[idx4];
            int4 c4 = cp4p[idx4];
            float4 bt4 = b4p[idx4];
            sids[k] = s4;
            int base_i = idx4 * 4;
            float bts[4] = {bt4.x, bt4.y, bt4.z, bt4.w};
            int   cps[4] = {c4.x, c4.y, c4.z, c4.w};
            int   ssd[4] = {s4.x, s4.y, s4.z, s4.w};
            #pragma unroll
            for (int e = 0; e < 4; ++e) {
                bool is1 = (cps[e] == 1);
                float bt = bts[e];
                float l = __logf(1.f + __expf(-fabsf(bt)));   // log(1+e^{-|x|})
                if (is1) {
                    a1 += l + fmaxf(-bt, 0.f);                // softplus(-bt)
                    posl++;
                    atomicMin(&s_first[ssd[e]], base_i + e);
                } else {
                    a2 += l + fmaxf(bt, 0.f);                 // softplus(bt)
                }
                atomicAdd(&s_counts[ssd[e]], 1);
                // ballot compaction: one LDS atomic per wave per sub-element
                unsigned long long m = __ballot(is1);
                int wbase = 0;
                if (lane == 0 && m != 0ull) wbase = atomicAdd(&s_cpn, __popcll(m));
                wbase = __shfl(wbase, 0);
                slots[k * 4 + e] = is1 ? (wbase + __popcll(m & ((1ull << lane) - 1ull))) : -1;
            }
        }

        // block reduction of a1, a2, pos (4 waves)
        float pf = (float)posl;
        #pragma unroll
        for (int o = 32; o > 0; o >>= 1) {
            a1 += __shfl_down(a1, o);
            a2 += __shfl_down(a2, o);
            pf += __shfl_down(pf, o);
        }
        if (lane == 0) { s_red[0][wid] = a1; s_red[1][wid] = a2; s_red[2][wid] = pf; }
        __syncthreads();   // s_first / s_counts / s_cpn / s_red final

        // stage first-CP embeddings
        if (t < KK) {
            int f = s_first[t]; if (f > NN - 1) f = NN - 1;
            const float4* fp = (const float4*)(emb_b + (size_t)f * 8);
            *(float4*)&s_fe[t][0] = fp[0];
            *(float4*)&s_fe[t][4] = fp[1];
        }
        __syncthreads();

        // attraction d2 seg-sums + CP embed compaction (single emb read)
        float* cpe_b = cpemb + (size_t)b * NN * 8;
        float* cpq_b = cpsq + (size_t)b * NN;
        const float S = 1.41421356237f;   // prescale: ea_i . ea_j = 2 dot
        #pragma unroll
        for (int k = 0; k < 4; ++k) {
            int ssd[4] = {sids[k].x, sids[k].y, sids[k].z, sids[k].w};
            #pragma unroll
            for (int e = 0; e < 4; ++e) {
                int i = (k * TPB + t) * 4 + e;
                const float4* ep = (const float4*)(emb_b + (size_t)i * 8);
                float4 e0 = ep[0], e1 = ep[1];
                float4 f0 = *(float4*)&s_fe[ssd[e]][0];
                float4 f1 = *(float4*)&s_fe[ssd[e]][4];
                float dx, d2 = 0.f;
                dx = e0.x - f0.x; d2 += dx * dx;
                dx = e0.y - f0.y; d2 += dx * dx;
                dx = e0.z - f0.z; d2 += dx * dx;
                dx = e0.w - f0.w; d2 += dx * dx;
                dx = e1.x - f1.x; d2 += dx * dx;
                dx = e1.y - f1.y; d2 += dx * dx;
                dx = e1.z - f1.z; d2 += dx * dx;
                dx = e1.w - f1.w; d2 += dx * dx;
                atomicAdd(&s_seg[ssd[e]], d2);
                int sl = slots[k * 4 + e];
                if (sl >= 0) {
                    float sq = e0.x*e0.x + e0.y*e0.y + e0.z*e0.z + e0.w*e0.w
                             + e1.x*e1.x + e1.y*e1.y + e1.z*e1.z + e1.w*e1.w;
                    float4* op = (float4*)(cpe_b + (size_t)sl * 8);
                    op[0] = make_float4(e0.x*S, e0.y*S, e0.z*S, e0.w*S);
                    op[1] = make_float4(e1.x*S, e1.y*S, e1.z*S, e1.w*S);
                    cpq_b[sl] = sq;
                }
            }
        }
        __syncthreads();

        // wave 0: attraction reduce + per-batch scalars
        if (t < KK) {
            int c = s_counts[t], f = s_first[t];
            float attr = (c > 0 && f < NN) ? s_seg[t] / (float)c : 0.f;
            #pragma unroll
            for (int o = 32; o > 0; o >>= 1) attr += __shfl_down(attr, o);
            if (t == 0) {
                float A1 = s_red[0][0] + s_red[0][1] + s_red[0][2] + s_red[0][3];
                float A2 = s_red[1][0] + s_red[1][1] + s_red[1][2] + s_red[1][3];
                float P  = s_red[2][0] + s_red[2][1] + s_red[2][2] + s_red[2][3];
                float neg = (float)NN - P;
                float bce = (neg / (P + 1e-6f) * A1 + A2) * (1.f / (float)NN);
                gbase[b] = bce + attr;
                gpos[b]  = P;
                grep[b]  = 0.f;
                gcpn[b]  = s_cpn;
            }
        }
    }

    grid.sync();

    // ================= phase 2: repulsion (all 256 blocks) ===================
    {
        const int b2  = blk >> 6;          // 64 blocks per batch
        const int jt0 = blk & 63;
        const int pos = gcpn[b2];
        const float* cpe2 = cpemb + (size_t)b2 * NN * 8;
        const float* cpq2 = cpsq + (size_t)b2 * NN;

        float sum = 0.f;
        for (int jbase = jt0 * JT; jbase < pos; jbase += BPB * JT) {
            int jn = pos - jbase; if (jn > JT) jn = JT;
            __syncthreads();               // protect s_je across iterations
            if (t < 64) {                  // 32 rows x 2 float4
                int row = t >> 1, half = t & 1;
                if (row < jn) {
                    *(float4*)&s_je[row * 8 + half * 4] =
                        *(const float4*)(cpe2 + (size_t)(jbase + row) * 8 + half * 4);
                    if (half == 0) s_jq[row] = cpq2[jbase + row];
                }
            }
            __syncthreads();

            for (int ibase = 0; ibase < pos; ibase += TPB * 4) {
                float4 e0[4], e1[4];
                float  nq[4];
                #pragma unroll
                for (int u = 0; u < 4; ++u) {
                    int i = ibase + u * TPB + t;
                    bool iv = (i < pos);
                    const float4* ip = (const float4*)(cpe2 + (size_t)(iv ? i : 0) * 8);
                    e0[u] = ip[0]; e1[u] = ip[1];
                    nq[u] = iv ? -cpq2[i] : -1e30f;   // exp -> 0 for pad lanes
                }
                #pragma unroll 2
                for (int j = 0; j < jn; ++j) {
                    float4 f0 = *(const float4*)&s_je[j * 8];   // wave-uniform
                    float4 f1 = *(const float4*)&s_je[j * 8 + 4];
                    float qj = s_jq[j];
                    #pragma unroll
                    for (int u = 0; u < 4; ++u) {
                        float arg = nq[u] - qj;
                        arg = fmaf(e0[u].x, f0.x, arg);
                        arg = fmaf(e0[u].y, f0.y, arg);
                        arg = fmaf(e0[u].z, f0.z, arg);
                        arg = fmaf(e0[u].w, f0.w, arg);
                        arg = fmaf(e1[u].x, f1.x, arg);
                        arg = fmaf(e1[u].y, f1.y, arg);
                        arg = fmaf(e1[u].z, f1.z, arg);
                        arg = fmaf(e1[u].w, f1.w, arg);
                        arg = fminf(arg, 0.f);        // maximum(d2, 0)
                        sum += __expf(arg);
                    }
                }
            }
        }
        #pragma unroll
        for (int o = 32; o > 0; o >>= 1) sum += __shfl_down(sum, o);
        if (lane == 0) s_r[wid] = sum;
        __syncthreads();
        if (t == 0) atomicAdd(&grep[b2], s_r[0] + s_r[1] + s_r[2] + s_r[3]);
    }

    grid.sync();

    // ================= phase 3: finalize (block 0, thread 0) =================
    if (blk == 0 && t == 0) {
        float tot = 0.f, cnt = 0.f;
        #pragma unroll
        for (int b = 0; b < BB; ++b) {
            float P = gpos[b];
            float neg = (float)NN - P;
            bool valid = (P >= 1.f) && (neg >= 1.f);
            float rp = (P > 1.f) ? grep[b] / fmaxf(P * P, 1.f) : 0.f;
            float ttl = gbase[b] + rp;      // gbase = bce + attr
            if (valid) { tot += ttl; cnt += 1.f; }
        }
        out[0] = (cnt > 0.f) ? tot / cnt : 0.f;
    }
}

// ---------------- launch -----------------------------------------------------
extern "C" void kernel_launch(void* const* d_in, const int* in_sizes, int n_in,
                              void* d_out, int out_size, void* d_ws, size_t ws_size,
                              hipStream_t stream) {
    const float* beta     = (const float*)d_in[0];
    const float* embed    = (const float*)d_in[1];
    const int*   slice_id = (const int*)d_in[2];
    const int*   is_cp    = (const int*)d_in[3];
    float* out = (float*)d_out;

    // workspace layout (no pre-init needed: phase 1 writes everything)
    float* cpemb = (float*)d_ws;                  // B*N*8
    float* cpsq  = cpemb + (size_t)BB * NN * 8;   // B*N
    float* gbase = cpsq + (size_t)BB * NN;        // B   (bce + attr)
    float* gpos  = gbase + BB;                    // B
    float* grep  = gpos + BB;                     // B
    int*   gcpn  = (int*)(grep + BB);             // B

    void* args[] = { (void*)&beta, (void*)&embed, (void*)&slice_id, (void*)&is_cp,
                     (void*)&cpemb, (void*)&cpsq, (void*)&gbase, (void*)&gpos,
                     (void*)&grep, (void*)&gcpn, (void*)&out };
    hipLaunchCooperativeKernel((void*)kAll, dim3(GRID), dim3(TPB), args, 0, stream);
}

// Round 5
// 87.736 us; speedup vs baseline: 1.7366x; 1.7366x over previous
//
#include <hip/hip_runtime.h>
#include <math.h>

#define BB 4
#define NN 4096
#define KK 64
#define IT 1024                     // k2 i-tile (256 thr x 4)
#define JT 32                       // k2 j-tile
#define K2_BLOCKS (BB * (NN/IT) * (NN/JT))   // 2048

// ---------------- kernel 1: full per-batch stats (one block per batch) -------
// BCE partials, first-cp, counts, attraction seg-sums, CP compaction with
// sqrt(2) prescale, per-batch scalars. Writes grep=0 (ws is poisoned).
__global__ __launch_bounds__(1024) void k1(
    const float* __restrict__ beta, const float* __restrict__ embed,
    const int* __restrict__ sid_g, const int* __restrict__ cp_g,
    float* __restrict__ cpemb, float* __restrict__ cpsq,
    float* __restrict__ gbase, float* __restrict__ gpos,
    float* __restrict__ grep, int* __restrict__ gcpn)
{
    const int b    = blockIdx.x;
    const int t    = threadIdx.x;
    const int lane = t & 63;
    const int wid  = t >> 6;          // 16 waves

    __shared__ int   s_first[KK];
    __shared__ int   s_counts[KK];
    __shared__ float s_seg[KK];
    __shared__ float s_fe[KK][8];
    __shared__ float r1[16], r2[16], r3[16];
    __shared__ int   s_cpn;

    if (t < KK) { s_first[t] = NN; s_counts[t] = 0; s_seg[t] = 0.f; }
    if (t == 0) s_cpn = 0;
    __syncthreads();

    const int4*   sid4 = (const int4*)(sid_g + (size_t)b * NN);
    const int4*   cp4  = (const int4*)(cp_g + (size_t)b * NN);
    const float4* bt4p = (const float4*)(beta + (size_t)b * NN);
    const float*  emb_b = embed + (size_t)b * NN * 8;

    int4   s4  = sid4[t];
    int4   c4  = cp4[t];
    float4 bt4 = bt4p[t];
    int ssd[4] = {s4.x, s4.y, s4.z, s4.w};
    int cps[4] = {c4.x, c4.y, c4.z, c4.w};
    float bts[4] = {bt4.x, bt4.y, bt4.z, bt4.w};

    float a1 = 0.f, a2 = 0.f;   // sum sp(-b) over y=1, sum sp(b) over y=0
    int posl = 0;
    int slots[4];

    #pragma unroll
    for (int e = 0; e < 4; ++e) {
        bool is1 = (cps[e] == 1);
        float bt = bts[e];
        float l = __logf(1.f + __expf(-fabsf(bt)));   // log(1+e^{-|x|})
        if (is1) {
            a1 += l + fmaxf(-bt, 0.f);                // softplus(-bt)
            posl++;
            atomicMin(&s_first[ssd[e]], 4 * t + e);
        } else {
            a2 += l + fmaxf(bt, 0.f);                 // softplus(bt)
        }
        atomicAdd(&s_counts[ssd[e]], 1);
        // ballot compaction: one LDS atomic per wave per round
        unsigned long long m = __ballot(is1);
        int wbase = 0;
        if (lane == 0 && m != 0ull) wbase = atomicAdd(&s_cpn, __popcll(m));
        wbase = __shfl(wbase, 0);
        slots[e] = is1 ? (wbase + __popcll(m & ((1ull << lane) - 1ull))) : -1;
    }

    // block reduction of a1, a2, pos
    float pf = (float)posl;
    #pragma unroll
    for (int o = 32; o > 0; o >>= 1) {
        a1 += __shfl_down(a1, o);
        a2 += __shfl_down(a2, o);
        pf += __shfl_down(pf, o);
    }
    if (lane == 0) { r1[wid] = a1; r2[wid] = a2; r3[wid] = pf; }
    __syncthreads();   // s_first / s_counts / s_cpn / r* final

    // stage first-CP embeddings
    if (t < KK) {
        int f = s_first[t]; if (f > NN - 1) f = NN - 1;
        const float4* fp = (const float4*)(emb_b + (size_t)f * 8);
        *(float4*)&s_fe[t][0] = fp[0];
        *(float4*)&s_fe[t][4] = fp[1];
    }
    __syncthreads();

    // attraction d2 seg-sums + CP compaction (each thread: 128B contig emb)
    float* cpe_b = cpemb + (size_t)b * NN * 8;
    float* cpq_b = cpsq + (size_t)b * NN;
    const float S = 1.41421356237f;   // prescale: ea_i . ea_j = 2 dot
    #pragma unroll
    for (int e = 0; e < 4; ++e) {
        int i = 4 * t + e;
        const float4* ep = (const float4*)(emb_b + (size_t)i * 8);
        float4 e0 = ep[0], e1 = ep[1];
        float4 f0 = *(float4*)&s_fe[ssd[e]][0];
        float4 f1 = *(float4*)&s_fe[ssd[e]][4];
        float dx, d2 = 0.f;
        dx = e0.x - f0.x; d2 += dx * dx;
        dx = e0.y - f0.y; d2 += dx * dx;
        dx = e0.z - f0.z; d2 += dx * dx;
        dx = e0.w - f0.w; d2 += dx * dx;
        dx = e1.x - f1.x; d2 += dx * dx;
        dx = e1.y - f1.y; d2 += dx * dx;
        dx = e1.z - f1.z; d2 += dx * dx;
        dx = e1.w - f1.w; d2 += dx * dx;
        atomicAdd(&s_seg[ssd[e]], d2);
        if (slots[e] >= 0) {
            float sq = e0.x*e0.x + e0.y*e0.y + e0.z*e0.z + e0.w*e0.w
                     + e1.x*e1.x + e1.y*e1.y + e1.z*e1.z + e1.w*e1.w;
            float4* op = (float4*)(cpe_b + (size_t)slots[e] * 8);
            op[0] = make_float4(e0.x*S, e0.y*S, e0.z*S, e0.w*S);
            op[1] = make_float4(e1.x*S, e1.y*S, e1.z*S, e1.w*S);
            cpq_b[slots[e]] = sq;
        }
    }
    __syncthreads();

    // wave 0: attraction reduce + per-batch scalars
    if (t < KK) {
        int c = s_counts[t], f = s_first[t];
        float attr = (c > 0 && f < NN) ? s_seg[t] / (float)c : 0.f;
        #pragma unroll
        for (int o = 32; o > 0; o >>= 1) attr += __shfl_down(attr, o);
        if (t == 0) {
            float A1 = 0.f, A2 = 0.f, P = 0.f;
            #pragma unroll
            for (int w = 0; w < 16; ++w) { A1 += r1[w]; A2 += r2[w]; P += r3[w]; }
            float neg = (float)NN - P;
            float bce = (neg / (P + 1e-6f) * A1 + A2) * (1.f / (float)NN);
            gbase[b] = bce + attr;
            gpos[b]  = P;
            grep[b]  = 0.f;
            gcpn[b]  = s_cpn;
        }
    }
}

// ---------------- kernel 2: repulsion tiles (4 i per thread) -----------------
__global__ __launch_bounds__(256) void k2(
    const float* __restrict__ cpemb, const float* __restrict__ cpsq,
    const int* __restrict__ gcpn, float* __restrict__ grep)
{
    const int blk = blockIdx.x;
    const int b   = blk >> 9;
    const int rem = blk & 511;
    const int it  = rem >> 7;     // 0..3
    const int jt  = rem & 127;    // 0..127
    const int t   = threadIdx.x;

    const int pos = gcpn[b];
    if (it * IT >= pos || jt * JT >= pos) return;   // block-uniform exit

    __shared__ float s_je[JT * 8];
    __shared__ float s_jq[JT];
    __shared__ float r[4];

    int jn = pos - jt * JT; if (jn > JT) jn = JT;
    const float* cpe_b = cpemb + (size_t)b * NN * 8;
    const float* cpq_b = cpsq + (size_t)b * NN;

    if (t < 64) {   // 32 rows x 2 float4
        int row = t >> 1, half = t & 1;
        if (row < jn) {
            *(float4*)&s_je[row * 8 + half * 4] =
                *(const float4*)(cpe_b + (size_t)(jt * JT + row) * 8 + half * 4);
            if (half == 0) s_jq[row] = cpq_b[jt * JT + row];
        }
    }
    __syncthreads();

    float4 e0[4], e1[4];
    float  nq[4];
    #pragma unroll
    for (int u = 0; u < 4; ++u) {
        int i = it * IT + u * 256 + t;
        bool iv = (i < pos);
        const float4* ip = (const float4*)(cpe_b + (size_t)(iv ? i : 0) * 8);
        e0[u] = ip[0]; e1[u] = ip[1];
        nq[u] = iv ? -cpq_b[i] : -1e30f;   // exp -> 0 for pad lanes
    }

    float sum = 0.f;
    #pragma unroll 2
    for (int j = 0; j < jn; ++j) {
        float4 f0 = *(const float4*)&s_je[j * 8];   // wave-uniform broadcast
        float4 f1 = *(const float4*)&s_je[j * 8 + 4];
        float qj = s_jq[j];
        #pragma unroll
        for (int u = 0; u < 4; ++u) {
            float arg = nq[u] - qj;
            arg = fmaf(e0[u].x, f0.x, arg);
            arg = fmaf(e0[u].y, f0.y, arg);
            arg = fmaf(e0[u].z, f0.z, arg);
            arg = fmaf(e0[u].w, f0.w, arg);
            arg = fmaf(e1[u].x, f1.x, arg);
            arg = fmaf(e1[u].y, f1.y, arg);
            arg = fmaf(e1[u].z, f1.z, arg);
            arg = fmaf(e1[u].w, f1.w, arg);
            arg = fminf(arg, 0.f);          // maximum(d2, 0)
            sum += __expf(arg);
        }
    }
    #pragma unroll
    for (int o = 32; o > 0; o >>= 1) sum += __shfl_down(sum, o);
    if ((t & 63) == 0) r[t >> 6] = sum;
    __syncthreads();
    if (t == 0) atomicAdd(&grep[b], r[0] + r[1] + r[2] + r[3]);
}

// ---------------- kernel 3: finalize -----------------------------------------
__global__ __launch_bounds__(64) void k3(
    const float* __restrict__ gbase, const float* __restrict__ gpos,
    const float* __restrict__ grep, float* __restrict__ out)
{
    if (threadIdx.x == 0) {
        float tot = 0.f, cnt = 0.f;
        #pragma unroll
        for (int b = 0; b < BB; ++b) {
            float P = gpos[b];
            float neg = (float)NN - P;
            bool valid = (P >= 1.f) && (neg >= 1.f);
            float rp = (P > 1.f) ? grep[b] / fmaxf(P * P, 1.f) : 0.f;
            float ttl = gbase[b] + rp;      // gbase = bce + attr
            if (valid) { tot += ttl; cnt += 1.f; }
        }
        out[0] = (cnt > 0.f) ? tot / cnt : 0.f;
    }
}

// ---------------- launch -----------------------------------------------------
extern "C" void kernel_launch(void* const* d_in, const int* in_sizes, int n_in,
                              void* d_out, int out_size, void* d_ws, size_t ws_size,
                              hipStream_t stream) {
    const float* beta     = (const float*)d_in[0];
    const float* embed    = (const float*)d_in[1];
    const int*   slice_id = (const int*)d_in[2];
    const int*   is_cp    = (const int*)d_in[3];
    float* out = (float*)d_out;

    // workspace layout (k1 writes everything that is later read)
    float* cpemb = (float*)d_ws;                  // B*N*8
    float* cpsq  = cpemb + (size_t)BB * NN * 8;   // B*N
    float* gbase = cpsq + (size_t)BB * NN;        // B   (bce + attr)
    float* gpos  = gbase + BB;                    // B
    float* grep  = gpos + BB;                     // B
    int*   gcpn  = (int*)(grep + BB);             // B

    k1<<<BB, 1024, 0, stream>>>(beta, embed, slice_id, is_cp,
                                cpemb, cpsq, gbase, gpos, grep, gcpn);
    k2<<<K2_BLOCKS, 256, 0, stream>>>(cpemb, cpsq, gcpn, grep);
    k3<<<1, 64, 0, stream>>>(gbase, gpos, grep, out);
}

// Round 6
// 82.554 us; speedup vs baseline: 1.8456x; 1.0628x over previous
//
#include <hip/hip_runtime.h>
#include <math.h>

#define BB 4
#define NN 4096
#define KK 64
#define IT 1024                        // repulsion i-tile (256 thr x 4)
#define JT 32                          // repulsion j-tile
#define RB (BB * (NN/IT) * (NN/JT))    // 2048 repulsion blocks
#define ABLK 16                        // attraction blocks per batch
#define K2_BLOCKS (RB + BB * ABLK)     // 2112

// ---------------- kernel 1: per-batch stats + CP compaction ------------------
// One block per batch. BCE partials, first-cp, counts, CP compaction with
// sqrt(2) prescale. Writes per-batch scalars pre-scaled for k2's direct
// accumulation into out. Block 0 zeroes out (ws/out are poisoned each call).
__global__ __launch_bounds__(1024) void k1(
    const float* __restrict__ beta, const float* __restrict__ embed,
    const int* __restrict__ sid_g, const int* __restrict__ cp_g,
    float* __restrict__ cpemb, float* __restrict__ cpsq,
    int* __restrict__ gfirst, float* __restrict__ gwinv,
    float* __restrict__ gval, float* __restrict__ gbce_v,
    float* __restrict__ grwt, int* __restrict__ gcpn,
    float* __restrict__ out)
{
    const int b    = blockIdx.x;
    const int t    = threadIdx.x;
    const int lane = t & 63;
    const int wid  = t >> 6;          // 16 waves

    __shared__ int   s_first[KK];
    __shared__ int   s_counts[KK];
    __shared__ float r1[16], r2[16], r3[16];
    __shared__ int   s_cpn;

    if (t < KK) { s_first[t] = NN; s_counts[t] = 0; }
    if (t == 0) s_cpn = 0;
    __syncthreads();

    const int4*   sid4 = (const int4*)(sid_g + (size_t)b * NN);
    const int4*   cp4  = (const int4*)(cp_g + (size_t)b * NN);
    const float4* bt4p = (const float4*)(beta + (size_t)b * NN);
    const float*  emb_b = embed + (size_t)b * NN * 8;
    float* cpe_b = cpemb + (size_t)b * NN * 8;
    float* cpq_b = cpsq + (size_t)b * NN;

    int4   s4  = sid4[t];
    int4   c4  = cp4[t];
    float4 bt4 = bt4p[t];
    int ssd[4] = {s4.x, s4.y, s4.z, s4.w};
    int cps[4] = {c4.x, c4.y, c4.z, c4.w};
    float bts[4] = {bt4.x, bt4.y, bt4.z, bt4.w};

    float a1 = 0.f, a2 = 0.f;   // sum sp(-b) over y=1, sum sp(b) over y=0
    int posl = 0;
    const float S = 1.41421356237f;   // prescale: ea_i . ea_j = 2 dot

    #pragma unroll
    for (int e = 0; e < 4; ++e) {
        bool is1 = (cps[e] == 1);
        float bt = bts[e];
        float l = __logf(1.f + __expf(-fabsf(bt)));   // log(1+e^{-|x|})
        if (is1) {
            a1 += l + fmaxf(-bt, 0.f);                // softplus(-bt)
            posl++;
            atomicMin(&s_first[ssd[e]], 4 * t + e);
        } else {
            a2 += l + fmaxf(bt, 0.f);                 // softplus(bt)
        }
        atomicAdd(&s_counts[ssd[e]], 1);
        // ballot compaction: one LDS atomic per wave per round
        unsigned long long m = __ballot(is1);
        int wbase = 0;
        if (lane == 0 && m != 0ull) wbase = atomicAdd(&s_cpn, __popcll(m));
        wbase = __shfl(wbase, 0);
        if (is1) {
            int slot = wbase + __popcll(m & ((1ull << lane) - 1ull));
            const float4* ep = (const float4*)(emb_b + (size_t)(4 * t + e) * 8);
            float4 e0 = ep[0], e1 = ep[1];
            float sq = e0.x*e0.x + e0.y*e0.y + e0.z*e0.z + e0.w*e0.w
                     + e1.x*e1.x + e1.y*e1.y + e1.z*e1.z + e1.w*e1.w;
            float4* op = (float4*)(cpe_b + (size_t)slot * 8);
            op[0] = make_float4(e0.x*S, e0.y*S, e0.z*S, e0.w*S);
            op[1] = make_float4(e1.x*S, e1.y*S, e1.z*S, e1.w*S);
            cpq_b[slot] = sq;
        }
    }

    // block reduction of a1, a2, pos
    float pf = (float)posl;
    #pragma unroll
    for (int o = 32; o > 0; o >>= 1) {
        a1 += __shfl_down(a1, o);
        a2 += __shfl_down(a2, o);
        pf += __shfl_down(pf, o);
    }
    if (lane == 0) { r1[wid] = a1; r2[wid] = a2; r3[wid] = pf; }
    __syncthreads();   // s_first / s_counts / s_cpn / r* final

    if (t < KK) {
        int f = s_first[t], c = s_counts[t];
        gfirst[b * KK + t] = f;
        gwinv[b * KK + t]  = (f < NN && c > 0) ? 1.f / (float)c : 0.f;
    }
    if (t == 0) {
        float A1 = 0.f, A2 = 0.f, P = 0.f;
        #pragma unroll
        for (int w = 0; w < 16; ++w) { A1 += r1[w]; A2 += r2[w]; P += r3[w]; }
        float neg = (float)NN - P;
        float bce = (neg / (P + 1e-6f) * A1 + A2) * (1.f / (float)NN);
        float val = ((P >= 1.f) && (neg >= 1.f)) ? 1.f : 0.f;
        gval[b]   = val;
        gbce_v[b] = val * bce;
        grwt[b]   = (P > 1.f) ? val / (P * P) : 0.f;
        gcpn[b]   = s_cpn;
        if (b == 0) out[0] = 0.f;   // k2 runs after k1: safe init
    }
}

// ---------------- kernel 2: repulsion + attraction, direct to out ------------
__global__ __launch_bounds__(256) void k2(
    const float* __restrict__ embed, const int* __restrict__ sid_g,
    const float* __restrict__ cpemb, const float* __restrict__ cpsq,
    const int* __restrict__ gfirst, const float* __restrict__ gwinv,
    const float* __restrict__ gval, const float* __restrict__ gbce_v,
    const float* __restrict__ grwt, const int* __restrict__ gcpn,
    float* __restrict__ out)
{
    const int blk = blockIdx.x;
    const int t   = threadIdx.x;

    __shared__ float s_je[JT * 8];
    __shared__ float s_jq[JT];
    __shared__ float s_fe[KK][8];
    __shared__ float s_winv[KK];
    __shared__ float s_r[4];

    if (blk < RB) {
        // ---------------- repulsion tile ----------------
        const int b   = blk >> 9;
        const int rem = blk & 511;
        const int it  = rem >> 7;     // 0..3
        const int jt  = rem & 127;    // 0..127
        const int pos = gcpn[b];
        if (it * IT >= pos || jt * JT >= pos) return;   // block-uniform exit

        int jn = pos - jt * JT; if (jn > JT) jn = JT;
        const float* cpe_b = cpemb + (size_t)b * NN * 8;
        const float* cpq_b = cpsq + (size_t)b * NN;

        if (t < 64) {   // 32 rows x 2 float4
            int row = t >> 1, half = t & 1;
            if (row < jn) {
                *(float4*)&s_je[row * 8 + half * 4] =
                    *(const float4*)(cpe_b + (size_t)(jt * JT + row) * 8 + half * 4);
                if (half == 0) s_jq[row] = cpq_b[jt * JT + row];
            }
        }
        __syncthreads();

        float4 e0[4], e1[4];
        float  nq[4];
        #pragma unroll
        for (int u = 0; u < 4; ++u) {
            int i = it * IT + u * 256 + t;
            bool iv = (i < pos);
            const float4* ip = (const float4*)(cpe_b + (size_t)(iv ? i : 0) * 8);
            e0[u] = ip[0]; e1[u] = ip[1];
            nq[u] = iv ? -cpq_b[i] : -1e30f;   // exp -> 0 for pad lanes
        }

        float sum = 0.f;
        #pragma unroll 2
        for (int j = 0; j < jn; ++j) {
            float4 f0 = *(const float4*)&s_je[j * 8];   // wave-uniform broadcast
            float4 f1 = *(const float4*)&s_je[j * 8 + 4];
            float qj = s_jq[j];
            #pragma unroll
            for (int u = 0; u < 4; ++u) {
                float arg = nq[u] - qj;
                arg = fmaf(e0[u].x, f0.x, arg);
                arg = fmaf(e0[u].y, f0.y, arg);
                arg = fmaf(e0[u].z, f0.z, arg);
                arg = fmaf(e0[u].w, f0.w, arg);
                arg = fmaf(e1[u].x, f1.x, arg);
                arg = fmaf(e1[u].y, f1.y, arg);
                arg = fmaf(e1[u].z, f1.z, arg);
                arg = fmaf(e1[u].w, f1.w, arg);
                arg = fminf(arg, 0.f);          // maximum(d2, 0)
                sum += __expf(arg);
            }
        }
        #pragma unroll
        for (int o = 32; o > 0; o >>= 1) sum += __shfl_down(sum, o);
        if ((t & 63) == 0) s_r[t >> 6] = sum;
        __syncthreads();
        if (t == 0) {
            float part = s_r[0] + s_r[1] + s_r[2] + s_r[3];
            float cnt = gval[0] + gval[1] + gval[2] + gval[3];
            float ic = (cnt > 0.f) ? 1.f / cnt : 0.f;
            atomicAdd(out, part * grwt[b] * ic);
        }
    } else {
        // ---------------- attraction block ----------------
        const int ab  = blk - RB;
        const int b   = ab >> 4;          // ABLK = 16 per batch
        const int s16 = ab & 15;
        const float* emb_b = embed + (size_t)b * NN * 8;

        if (t < KK) {
            int f = gfirst[b * KK + t];
            if (f > NN - 1) f = NN - 1;
            const float4* fp = (const float4*)(emb_b + (size_t)f * 8);
            *(float4*)&s_fe[t][0] = fp[0];
            *(float4*)&s_fe[t][4] = fp[1];
            s_winv[t] = gwinv[b * KK + t];
        }
        __syncthreads();

        int i = s16 * 256 + t;
        int sid = sid_g[(size_t)b * NN + i];
        const float4* ep = (const float4*)(emb_b + (size_t)i * 8);
        float4 e0 = ep[0], e1 = ep[1];
        float4 f0 = *(float4*)&s_fe[sid][0];
        float4 f1 = *(float4*)&s_fe[sid][4];
        float dx, d2 = 0.f;
        dx = e0.x - f0.x; d2 += dx * dx;
        dx = e0.y - f0.y; d2 += dx * dx;
        dx = e0.z - f0.z; d2 += dx * dx;
        dx = e0.w - f0.w; d2 += dx * dx;
        dx = e1.x - f1.x; d2 += dx * dx;
        dx = e1.y - f1.y; d2 += dx * dx;
        dx = e1.z - f1.z; d2 += dx * dx;
        dx = e1.w - f1.w; d2 += dx * dx;
        float acc = d2 * s_winv[sid];

        #pragma unroll
        for (int o = 32; o > 0; o >>= 1) acc += __shfl_down(acc, o);
        if ((t & 63) == 0) s_r[t >> 6] = acc;
        __syncthreads();
        if (t == 0) {
            float part = s_r[0] + s_r[1] + s_r[2] + s_r[3];
            float cnt = gval[0] + gval[1] + gval[2] + gval[3];
            float ic = (cnt > 0.f) ? 1.f / cnt : 0.f;
            float contrib = part * gval[b];
            if (s16 == 0) contrib += gbce_v[b];   // bce added once per batch
            atomicAdd(out, contrib * ic);
        }
    }
}

// ---------------- launch -----------------------------------------------------
extern "C" void kernel_launch(void* const* d_in, const int* in_sizes, int n_in,
                              void* d_out, int out_size, void* d_ws, size_t ws_size,
                              hipStream_t stream) {
    const float* beta     = (const float*)d_in[0];
    const float* embed    = (const float*)d_in[1];
    const int*   slice_id = (const int*)d_in[2];
    const int*   is_cp    = (const int*)d_in[3];
    float* out = (float*)d_out;

    // workspace layout (k1 writes everything that is later read)
    float* cpemb  = (float*)d_ws;                   // B*N*8
    float* cpsq   = cpemb + (size_t)BB * NN * 8;    // B*N
    float* gwinv  = cpsq + (size_t)BB * NN;         // B*K
    float* gval   = gwinv + BB * KK;                // B
    float* gbce_v = gval + BB;                      // B
    float* grwt   = gbce_v + BB;                    // B
    int*   gfirst = (int*)(grwt + BB);              // B*K
    int*   gcpn   = gfirst + BB * KK;               // B

    k1<<<BB, 1024, 0, stream>>>(beta, embed, slice_id, is_cp,
                                cpemb, cpsq, gfirst, gwinv,
                                gval, gbce_v, grwt, gcpn, out);
    k2<<<K2_BLOCKS, 256, 0, stream>>>(embed, slice_id, cpemb, cpsq,
                                      gfirst, gwinv, gval, gbce_v,
                                      grwt, gcpn, out);
}